// Round 4
// baseline (176.596 us; speedup 1.0000x reference)
//
#include <hip/hip_runtime.h>

// F=32 fields, B=8192 batch, D=64.
// out[b, r*64+c] = s[b,r]*s[b,c], s[b,d] = sum_f in[f,b,0,d].
// Memory-bound: 64 MiB read + 128 MiB write -> ~32-37 us floor (mixed R/W).
//
// One wave owns 4 consecutive samples; waves are fully independent:
//   lane = lb*16 + dv  (lb = sample-in-wave, dv = float4 chunk of D)
//   Stage 1: per-lane field sum, 1 KiB contiguous per wave-load, no reduction.
//   Stage 2: LDS round-trip is WAVE-LOCAL (each wave reads only what it wrote;
//            DS ops from one wave execute in order) -> NO __syncthreads, so a
//            wave starts streaming stores as soon as its own loads complete.

#define NF 32
#define NB 8192
#define ND 64

typedef float f4 __attribute__((ext_vector_type(4)));  // native vec for nontemporal builtins

__global__ __launch_bounds__(256) void opnn_outer_kernel(
    const float* __restrict__ in, float* __restrict__ out) {
    const int tid  = threadIdx.x;
    const int w    = tid >> 6;        // wave in block: 0..3
    const int lane = tid & 63;
    const int lb   = lane >> 4;       // sample within wave: 0..3
    const int dv   = lane & 15;       // float4 index within D
    const int b0   = blockIdx.x * 16 + w * 4;  // this wave's first sample
    const int b    = b0 + lb;

    // ---- Stage 1: per-lane field sum (no cross-lane reduction) ----
    const f4* __restrict__ in4 = (const f4*)in;
    const size_t base = (size_t)b * (ND / 4) + dv;
    f4 acc = __builtin_nontemporal_load(&in4[base]);
    #pragma unroll
    for (int f = 1; f < NF; ++f)
        acc += __builtin_nontemporal_load(&in4[base + (size_t)f * NB * (ND / 4)]);

    __shared__ f4 sh[4][4][16];       // [wave][sample-in-wave][dv] -- wave-private
    sh[w][lb][dv] = acc;
    __builtin_amdgcn_wave_barrier();  // scheduling fence only; no block barrier needed

    // ---- Stage 2: outer product, 1 KiB contiguous per store instruction ----
    const float* shf = (const float*)&sh[w][0][0];
    #pragma unroll
    for (int ss = 0; ss < 4; ++ss) {
        const f4 sc = sh[w][ss][dv];                       // column vec, hoisted
        f4* __restrict__ outp = (f4*)(out + (size_t)(b0 + ss) * (ND * ND));
        #pragma unroll
        for (int it = 0; it < 16; ++it) {
            const float sr = shf[ss * 64 + it * 4 + lb];   // 4 addrs, 16x broadcast
            __builtin_nontemporal_store(sr * sc, &outp[it * 64 + lane]);
        }
    }
}

extern "C" void kernel_launch(void* const* d_in, const int* in_sizes, int n_in,
                              void* d_out, int out_size, void* d_ws, size_t ws_size,
                              hipStream_t stream) {
    const float* in = (const float*)d_in[0];
    float* out = (float*)d_out;
    opnn_outer_kernel<<<NB / 16, 256, 0, stream>>>(in, out);
}